// Round 11
// baseline (585.254 us; speedup 1.0000x reference)
//
#include <hip/hip_runtime.h>

typedef unsigned short u16;
typedef __attribute__((ext_vector_type(8))) short bf16x8;
typedef __attribute__((ext_vector_type(4))) float f32x4;

// Problem constants
#define LSEQ 512
#define BN   64
#define DD   128
#define HH   128
#define CHUNK 128   // embed rows staged in LDS per refill (32 KiB bf16)

// fp32 inputs (verified R7 diagnostic); one fp32 scalar output (R8-R10 PASS).

__device__ __forceinline__ u16 f2b(float f) {
  union { float f; unsigned i; } v; v.f = f;
  unsigned i = v.i;
  return (u16)((i + 0x7fffu + ((i >> 16) & 1u)) >> 16);
}
__device__ __forceinline__ float sigm(float x) {
  return 1.f / (1.f + __expf(-x));
}
__device__ __forceinline__ float tanh_f(float x) {
  x = fminf(15.f, fmaxf(-15.f, x));
  float e = __expf(2.f * x);
  return (e - 1.f) / (e + 1.f);
}
__device__ __forceinline__ float clampg(float x, float hi) {
  return fmaxf(-hi, fminf(hi, x));  // transparent: true |gates|<0.5
}

// ---------------------------------------------------------------------------
// Two 512-step recurrences, fused. blockIdx 0..63: fwd LSTM sample b;
// 64..127: tree-LSTM chain (left-deep). Block = 512 threads (8 waves).
// Tile g of wave w covers gate columns n = g*128 + w*16 + lr => lanes 0..15
// of wave w hold ALL FOUR gates of d = w*16+lr in acc[0..3][0] (wave-local
// nonlinearity, single barrier/step).
//
// KEY (round 11): ZERO global memory ops inside the step loop. Embed rows are
// pre-staged into LDS in CHUNK-row bursts (fp32->bf16, A-fragment-ready
// layout); the compiler's mandatory `s_waitcnt vmcnt(0)` before every
// s_barrier is then free. A-fragments: h from aK (LDS dbuf), e directly from
// the staged chunk. Weights resident in VGPRs (one-time fp32->bf16 build).
// ---------------------------------------------------------------------------
__global__ __launch_bounds__(512, 1) void chains_kernel(
    const int* __restrict__ x, const int* __restrict__ lengths,
    const float* __restrict__ embed,
    const float* __restrict__ Wih_f, const float* __restrict__ Whh_f,
    const float* __restrict__ b_f,
    const float* __restrict__ Wiou, const float* __restrict__ Uiou,
    const float* __restrict__ biou,
    const float* __restrict__ Wf, const float* __restrict__ Uf,
    const float* __restrict__ bfv,
    float* __restrict__ sent_vec, float* __restrict__ t_state,
    float* __restrict__ t_hidden) {
  const bool tree = blockIdx.x >= BN;
  const int b = blockIdx.x & (BN - 1);
  int len = lengths[b];
  len = (len < 1) ? 1 : (len > LSEQ ? LSEQ : len);
  const int tid = threadIdx.x;
  const int w = tid >> 6, l = tid & 63, lr = l & 15, lq = l >> 4;
  const int d = w * 16 + lr;  // hidden index owned by this lane (if l<16)

  __shared__ __align__(16) u16 echunk[CHUNK * 128];  // staged e rows, bf16
  __shared__ __align__(16) u16 aK[2][128];           // h bf16, double-buffered
  __shared__ int toks[LSEQ];                         // token ids (clamped)

  // ---- Resident B fragments (one-time). MFMA #ks of tile g consumes
  // B[k = ks*32 + lq*8 + j][n = g*128 + w*16 + lr], j = 0..7.
  bf16x8 bfrag[4][8];
  if (!tree) {
#pragma unroll
    for (int g = 0; g < 4; g++) {
      const int n = g * 128 + w * 16 + lr;
#pragma unroll
      for (int ks = 0; ks < 8; ks++) {
        const int k0 = ks * 32 + lq * 8;  // multiple of 8; never straddles 128
        const float* src = (k0 < 128) ? (Whh_f + n * 128 + k0)
                                      : (Wih_f + n * 128 + (k0 - 128));
        float4 lo = *(const float4*)src;
        float4 hi = *(const float4*)(src + 4);
        bf16x8 fr;
        fr[0] = (short)f2b(lo.x); fr[1] = (short)f2b(lo.y);
        fr[2] = (short)f2b(lo.z); fr[3] = (short)f2b(lo.w);
        fr[4] = (short)f2b(hi.x); fr[5] = (short)f2b(hi.y);
        fr[6] = (short)f2b(hi.z); fr[7] = (short)f2b(hi.w);
        bfrag[g][ks] = fr;
      }
    }
  } else {
#pragma unroll
    for (int g = 0; g < 4; g++) {
      const int col = (g < 3) ? (g * 128 + w * 16 + lr) : (w * 16 + lr);
#pragma unroll
      for (int ks = 0; ks < 8; ks++) {
        const int k0 = ks * 32 + lq * 8;
        bf16x8 fr;
#pragma unroll
        for (int j = 0; j < 8; j++) {
          const int k = k0 + j;
          float v;
          if (g < 3) v = (k < 128) ? Uiou[k * 384 + col]
                                   : Wiou[(k - 128) * 384 + col];
          else       v = (k < 128) ? Uf[k * 128 + col]
                                   : Wf[(k - 128) * 128 + col];
          fr[j] = (short)f2b(v);
        }
        bfrag[g][ks] = fr;
      }
    }
  }

  // Per-lane biases for the 4 gates of d (lanes 0..15 of each wave).
  float bias0 = 0.f, bias1 = 0.f, bias2 = 0.f, bias3 = 0.f;
  if (l < 16) {
    if (!tree) {
      bias0 = b_f[d];        bias1 = b_f[128 + d];
      bias2 = b_f[256 + d];  bias3 = b_f[384 + d];
    } else {
      bias0 = biou[d];       bias1 = biou[128 + d];
      bias2 = biou[256 + d]; bias3 = bfv[d];
    }
  }

  // Token ids -> LDS (indices clamped to len-1 at fill time); h(0) = 0.
  for (int i = tid; i < LSEQ; i += 512) {
    int tt = (i < len) ? i : (len - 1);
    toks[i] = x[tt * BN + b];
  }
  if (tid < HH) { aK[0][tid] = 0; aK[1][tid] = 0; }

  float c = 0.f, h = 0.f;
  int t = 0;
  for (int c0 = 0; c0 < len; c0 += CHUNK) {
    __syncthreads();  // prev chunk fully consumed (and toks/h0 visible)

    // ---- Refill: stage rows [c0, c0+CHUNK) as bf16 into echunk.
    // 128 rows x 128 elems = 4096 float4 groups; 8 per thread, independent.
#pragma unroll
    for (int j = 0; j < 8; j++) {
      int u = tid + j * 512;        // float4 index in chunk
      int r = u >> 5;               // row within chunk
      int c4 = (u & 31) * 4;        // starting col
      int row = toks[c0 + r];       // pre-clamped
      float4 v = *(const float4*)(embed + (size_t)row * DD + c4);
      u16 eb[4] = {f2b(v.x), f2b(v.y), f2b(v.z), f2b(v.w)};
      *(unsigned long long*)&echunk[r * 128 + c4] =
          *(const unsigned long long*)eb;
    }
    __syncthreads();  // chunk visible

    const int tend = (c0 + CHUNK < len) ? c0 + CHUNK : len;
    for (; t < tend; t++) {
      const int cur = t & 1, nxt = cur ^ 1;

      // A fragments: h-part from aK[cur], e-part straight from echunk.
      bf16x8 a[8];
#pragma unroll
      for (int ks = 0; ks < 4; ks++)
        a[ks] = *(const bf16x8*)&aK[cur][ks * 32 + lq * 8];
      const u16* erow = &echunk[(t & (CHUNK - 1)) * 128];
#pragma unroll
      for (int ks = 0; ks < 4; ks++)
        a[4 + ks] = *(const bf16x8*)&erow[ks * 32 + lq * 8];

      f32x4 acc[4];
#pragma unroll
      for (int g = 0; g < 4; g++) acc[g] = (f32x4){0.f, 0.f, 0.f, 0.f};
#pragma unroll
      for (int g = 0; g < 4; g++)
#pragma unroll
        for (int ks = 0; ks < 8; ks++)
          acc[g] = __builtin_amdgcn_mfma_f32_16x16x32_bf16(a[ks], bfrag[g][ks],
                                                           acc[g], 0, 0, 0);

      // acc[g][0] in lanes 0..15 = gate g of d. Wave-local nonlinearity.
      if (l < 16) {
        float g0 = clampg(acc[0][0] + bias0, 16.f);
        float g1 = clampg(acc[1][0] + bias1, 16.f);
        float g2 = clampg(acc[2][0] + bias2, 16.f);
        float g3 = clampg(acc[3][0] + bias3, 16.f);
        if (!tree) {
          // PyTorch LSTM gate order: i, f, g, o
          float ii = sigm(g0), ff = sigm(g1), gg = tanh_f(g2), oo = sigm(g3);
          c = ff * c + ii * gg;
          h = oo * tanh_f(c);
        } else {
          // iou = (i,o,u); g3 = f gate; right child absent (hr=cr=0)
          float ii = sigm(g0), oo = sigm(g1), uu = tanh_f(g2), fl = sigm(g3);
          c = ii * uu + fl * c;
          h = oo * tanh_f(c);
        }
        aK[nxt][d] = f2b(h);
      }
      __syncthreads();  // h(t+1) visible; all reads of aK[cur]/echunk done
    }
  }

  if (l < 16) {
    if (!tree) {
      sent_vec[b * HH + d] = h;
    } else {
      t_state[b * HH + d] = c;
      t_hidden[b * HH + d] = h;
    }
  }
}

// ---------------------------------------------------------------------------
// Head: tree_out = [t_state | w1*t_hidden + w2*sent_vec]; sigmoid logits ->
// clipped BCE vs one-hot(y); loss = -mean over (B, NC=2) = 128 terms. fp32.
// ---------------------------------------------------------------------------
__global__ __launch_bounds__(128) void final_kernel(
    const int* __restrict__ y, const float* __restrict__ sent_vec,
    const float* __restrict__ t_state, const float* __restrict__ t_hidden,
    const float* __restrict__ Wout, const float* __restrict__ bout,
    const float* __restrict__ w1, const float* __restrict__ w2,
    float* __restrict__ out) {
  int tid = threadIdx.x;  // (b, cls)
  int b = tid >> 1, cls = tid & 1;
  float W1 = w1[0], W2 = w2[0];
  const float* wrow = Wout + cls * 256;
  float acc = bout[cls];
  for (int j = 0; j < HH; j++)
    acc += t_state[b * HH + j] * wrow[j];
  for (int j = 0; j < HH; j++)
    acc += (W1 * t_hidden[b * HH + j] + W2 * sent_vec[b * HH + j]) * wrow[128 + j];
  float p = 1.f / (1.f + __expf(-acc));
  p = fminf(1.f - 1e-7f, fmaxf(1e-7f, p));
  int yy = y[b]; yy = yy < 0 ? 0 : (yy > 1 ? 1 : yy);
  float term = (cls == yy) ? __logf(p) : __logf(1.f - p);
  __shared__ float red[128];
  red[tid] = term;
  __syncthreads();
  for (int s = 64; s > 0; s >>= 1) {
    if (tid < s) red[tid] += red[tid + s];
    __syncthreads();
  }
  if (tid == 0) out[0] = -red[0] / 128.f;
}

// ---------------------------------------------------------------------------
extern "C" void kernel_launch(void* const* d_in, const int* in_sizes, int n_in,
                              void* d_out, int out_size, void* d_ws, size_t ws_size,
                              hipStream_t stream) {
  (void)in_sizes; (void)n_in; (void)out_size; (void)ws_size;
  const int*   x       = (const int*)d_in[0];
  const int*   y       = (const int*)d_in[1];
  // d_in[2] = p (unused by reference)
  const int*   lengths = (const int*)d_in[3];
  // d_in[4], d_in[5] = left/right child: fixed left-deep chain (j-1 / -1)
  const float* embed   = (const float*)d_in[6];
  const float* Wih_f   = (const float*)d_in[7];
  const float* Whh_f   = (const float*)d_in[8];
  const float* b_f     = (const float*)d_in[9];
  // d_in[10..12] = backward-LSTM weights (result unused by reference)
  const float* Wiou    = (const float*)d_in[13];
  const float* Uiou    = (const float*)d_in[14];
  const float* biou    = (const float*)d_in[15];
  const float* Wf      = (const float*)d_in[16];
  const float* Uf      = (const float*)d_in[17];
  const float* bfv     = (const float*)d_in[18];
  const float* Wout    = (const float*)d_in[19];
  const float* bout    = (const float*)d_in[20];
  const float* w1      = (const float*)d_in[21];
  const float* w2      = (const float*)d_in[22];

  // Workspace: 3 fp32 [64][128] vectors = 96 KiB.
  float* sent_vec = (float*)d_ws;
  float* t_state  = sent_vec + BN * HH;
  float* t_hidden = t_state + BN * HH;

  chains_kernel<<<128, 512, 0, stream>>>(x, lengths, embed,
                                         Wih_f, Whh_f, b_f,
                                         Wiou, Uiou, biou, Wf, Uf, bfv,
                                         sent_vec, t_state, t_hidden);
  final_kernel<<<1, 128, 0, stream>>>(y, sent_vec, t_state, t_hidden,
                                      Wout, bout, w1, w2, (float*)d_out);
}

// Round 12
// 494.280 us; speedup vs baseline: 1.1841x; 1.1841x over previous
//
#include <hip/hip_runtime.h>

typedef unsigned short u16;
typedef __attribute__((ext_vector_type(8))) short bf16x8;
typedef __attribute__((ext_vector_type(4))) float f32x4;

// Problem constants
#define LSEQ 512
#define BN   64
#define DD   128
#define HH   128
#define CHUNK 128   // embed rows staged in LDS per refill (32 KiB bf16)

// fp32 inputs (verified R7 diagnostic); one fp32 scalar output (R8-R11 PASS).

__device__ __forceinline__ u16 f2b(float f) {
  union { float f; unsigned i; } v; v.f = f;
  unsigned i = v.i;
  return (u16)((i + 0x7fffu + ((i >> 16) & 1u)) >> 16);
}
__device__ __forceinline__ float rcpf(float x) {
  return __builtin_amdgcn_rcpf(x);
}
__device__ __forceinline__ float sigm(float x) {
  return rcpf(1.f + __expf(-x));               // v_exp + v_rcp, no div chain
}
__device__ __forceinline__ float tanh_f(float x) {
  x = fminf(15.f, fmaxf(-15.f, x));
  float e = __expf(2.f * x);
  return (e - 1.f) * rcpf(e + 1.f);
}
__device__ __forceinline__ float clampg(float x, float hi) {
  return fmaxf(-hi, fminf(hi, x));  // transparent: true |gates|<0.5
}

// ---------------------------------------------------------------------------
// Two 512-step recurrences, fused. blockIdx 0..63: fwd LSTM sample b;
// 64..127: tree-LSTM chain (left-deep). Block = 512 threads (8 waves).
// Tile g of wave w covers gate columns n = g*128 + w*16 + lr; C-rows are
// broadcast-identical, so EVERY lane holds all 4 gates of d = w*16 + (l&15).
//
// Round-12 critical-path surgery:
//  * K split: gates = Wh.h(t) + We.e(t). The e-half (4 ds_reads + 16 MFMAs)
//    is precomputed for t+1 during step t (doesn't depend on h) -> the
//    per-step dependent-MFMA chain depth drops 8 -> 4.
//  * MFMAs issued ks-outer/g-inner so the 4 gate-chains interleave.
//  * Zero-acc hoisted: first MFMA of each chain consumes a loop-invariant 0.
//  * rcp-based sigmoid/tanh (no fp32 division sequence on the serial path);
//    nonlinearity computed by all 64 lanes (no divergence), masked ds_write.
//  * Zero global memory ops inside the step loop (echunk staging, R11).
// ---------------------------------------------------------------------------
__global__ __launch_bounds__(512, 1) void chains_kernel(
    const int* __restrict__ x, const int* __restrict__ lengths,
    const float* __restrict__ embed,
    const float* __restrict__ Wih_f, const float* __restrict__ Whh_f,
    const float* __restrict__ b_f,
    const float* __restrict__ Wiou, const float* __restrict__ Uiou,
    const float* __restrict__ biou,
    const float* __restrict__ Wf, const float* __restrict__ Uf,
    const float* __restrict__ bfv,
    float* __restrict__ sent_vec, float* __restrict__ t_state,
    float* __restrict__ t_hidden) {
  const bool tree = blockIdx.x >= BN;
  const int b = blockIdx.x & (BN - 1);
  int len = lengths[b];
  len = (len < 1) ? 1 : (len > LSEQ ? LSEQ : len);
  const int tid = threadIdx.x;
  const int w = tid >> 6, l = tid & 63, lr = l & 15, lq = l >> 4;
  const int d = w * 16 + lr;  // hidden index this lane's gates belong to

  __shared__ __align__(16) u16 echunk[CHUNK * 128];  // staged e rows, bf16
  __shared__ __align__(16) u16 aK[2][128];           // h bf16, double-buffered
  __shared__ int toks[LSEQ];                         // token ids (clamped)

  // ---- Resident B fragments, split into h-half (k<128) and e-half (k>=128).
  // MFMA #ks consumes B[k = ks*32 + lq*8 + j][n], j = 0..7.
  bf16x8 bfragH[4][4], bfragE[4][4];
  if (!tree) {
#pragma unroll
    for (int g = 0; g < 4; g++) {
      const int n = g * 128 + w * 16 + lr;
#pragma unroll
      for (int ks = 0; ks < 4; ks++) {
        const int k0 = ks * 32 + lq * 8;
        {
          float4 lo = *(const float4*)(Whh_f + n * 128 + k0);
          float4 hi = *(const float4*)(Whh_f + n * 128 + k0 + 4);
          bf16x8 fr;
          fr[0] = (short)f2b(lo.x); fr[1] = (short)f2b(lo.y);
          fr[2] = (short)f2b(lo.z); fr[3] = (short)f2b(lo.w);
          fr[4] = (short)f2b(hi.x); fr[5] = (short)f2b(hi.y);
          fr[6] = (short)f2b(hi.z); fr[7] = (short)f2b(hi.w);
          bfragH[g][ks] = fr;
        }
        {
          float4 lo = *(const float4*)(Wih_f + n * 128 + k0);
          float4 hi = *(const float4*)(Wih_f + n * 128 + k0 + 4);
          bf16x8 fr;
          fr[0] = (short)f2b(lo.x); fr[1] = (short)f2b(lo.y);
          fr[2] = (short)f2b(lo.z); fr[3] = (short)f2b(lo.w);
          fr[4] = (short)f2b(hi.x); fr[5] = (short)f2b(hi.y);
          fr[6] = (short)f2b(hi.z); fr[7] = (short)f2b(hi.w);
          bfragE[g][ks] = fr;
        }
      }
    }
  } else {
#pragma unroll
    for (int g = 0; g < 4; g++) {
      const int col = (g < 3) ? (g * 128 + w * 16 + lr) : (w * 16 + lr);
#pragma unroll
      for (int ks = 0; ks < 4; ks++) {
        const int k0 = ks * 32 + lq * 8;
        bf16x8 fh, fe;
#pragma unroll
        for (int j = 0; j < 8; j++) {
          const int k = k0 + j;
          float vh, ve;
          if (g < 3) { vh = Uiou[k * 384 + col]; ve = Wiou[k * 384 + col]; }
          else       { vh = Uf[k * 128 + col];   ve = Wf[k * 128 + col]; }
          fh[j] = (short)f2b(vh);
          fe[j] = (short)f2b(ve);
        }
        bfragH[g][ks] = fh;
        bfragE[g][ks] = fe;
      }
    }
  }

  // Per-lane biases for the 4 gates of d (all lanes; quadrants identical).
  float bias0, bias1, bias2, bias3;
  if (!tree) {
    bias0 = b_f[d];        bias1 = b_f[128 + d];
    bias2 = b_f[256 + d];  bias3 = b_f[384 + d];
  } else {
    bias0 = biou[d];       bias1 = biou[128 + d];
    bias2 = biou[256 + d]; bias3 = bfv[d];
  }

  // Token ids -> LDS (clamped); h(0) = 0 in both buffers.
  for (int i = tid; i < LSEQ; i += 512) {
    int tt = (i < len) ? i : (len - 1);
    toks[i] = x[tt * BN + b];
  }
  if (tid < HH) { aK[0][tid] = 0; aK[1][tid] = 0; }

  const f32x4 zf = (f32x4){0.f, 0.f, 0.f, 0.f};
  f32x4 eA[4], eB[4];
  float c = 0.f, h = 0.f;
  int t = 0;

#define EPRE(EDST, ROW)                                                       \
  {                                                                           \
    const u16* er = &echunk[(ROW) * 128];                                     \
    bf16x8 ae[4];                                                             \
    _Pragma("unroll")                                                         \
    for (int ks = 0; ks < 4; ks++)                                            \
      ae[ks] = *(const bf16x8*)&er[ks * 32 + lq * 8];                         \
    _Pragma("unroll")                                                         \
    for (int g = 0; g < 4; g++)                                               \
      EDST[g] = __builtin_amdgcn_mfma_f32_16x16x32_bf16(ae[0], bfragE[g][0],  \
                                                        zf, 0, 0, 0);         \
    _Pragma("unroll")                                                         \
    for (int ks = 1; ks < 4; ks++)                                            \
      _Pragma("unroll")                                                       \
      for (int g = 0; g < 4; g++)                                             \
        EDST[g] = __builtin_amdgcn_mfma_f32_16x16x32_bf16(                    \
            ae[ks], bfragE[g][ks], EDST[g], 0, 0, 0);                         \
  }

#define STEP(ECUR, ENXT)                                                      \
  {                                                                           \
    const int cur = t & 1, nxt = cur ^ 1;                                     \
    bf16x8 ah[4];                                                             \
    _Pragma("unroll")                                                         \
    for (int ks = 0; ks < 4; ks++)                                            \
      ah[ks] = *(const bf16x8*)&aK[cur][ks * 32 + lq * 8];                    \
    f32x4 acch[4];                                                            \
    _Pragma("unroll")                                                         \
    for (int g = 0; g < 4; g++)                                               \
      acch[g] = __builtin_amdgcn_mfma_f32_16x16x32_bf16(ah[0], bfragH[g][0],  \
                                                        zf, 0, 0, 0);         \
    _Pragma("unroll")                                                         \
    for (int ks = 1; ks < 4; ks++)                                            \
      _Pragma("unroll")                                                       \
      for (int g = 0; g < 4; g++)                                             \
        acch[g] = __builtin_amdgcn_mfma_f32_16x16x32_bf16(                    \
            ah[ks], bfragH[g][ks], acch[g], 0, 0, 0);                         \
    if (t + 1 < tend) { EPRE(ENXT, ((t + 1) & (CHUNK - 1))) }                 \
    float g0 = clampg(acch[0][0] + ECUR[0][0] + bias0, 16.f);                 \
    float g1 = clampg(acch[1][0] + ECUR[1][0] + bias1, 16.f);                 \
    float g2 = clampg(acch[2][0] + ECUR[2][0] + bias2, 16.f);                 \
    float g3 = clampg(acch[3][0] + ECUR[3][0] + bias3, 16.f);                 \
    if (!tree) {                                                              \
      float ii = sigm(g0), ff = sigm(g1), gg = tanh_f(g2), oo = sigm(g3);     \
      c = ff * c + ii * gg;                                                   \
      h = oo * tanh_f(c);                                                     \
    } else {                                                                  \
      float ii = sigm(g0), oo = sigm(g1), uu = tanh_f(g2), fl = sigm(g3);     \
      c = ii * uu + fl * c;                                                   \
      h = oo * tanh_f(c);                                                     \
    }                                                                         \
    if (l < 16) aK[nxt][d] = f2b(h);                                          \
    __syncthreads();                                                          \
    t++;                                                                      \
  }

  for (int c0 = 0; c0 < len; c0 += CHUNK) {
    __syncthreads();  // prev chunk fully consumed (and toks/h0 visible)

    // ---- Refill: stage rows [c0, c0+CHUNK) as bf16 into echunk.
#pragma unroll
    for (int j = 0; j < 8; j++) {
      int u = tid + j * 512;
      int r = u >> 5;
      int c4 = (u & 31) * 4;
      int row = toks[c0 + r];
      float4 v = *(const float4*)(embed + (size_t)row * DD + c4);
      u16 eb[4] = {f2b(v.x), f2b(v.y), f2b(v.z), f2b(v.w)};
      *(unsigned long long*)&echunk[r * 128 + c4] =
          *(const unsigned long long*)eb;
    }
    __syncthreads();  // chunk visible

    const int tend = (c0 + CHUNK < len) ? c0 + CHUNK : len;
    EPRE(eA, (t & (CHUNK - 1)))   // acc_e for first step of chunk (t even)
    while (t < tend) {
      STEP(eA, eB)
      if (t >= tend) break;
      STEP(eB, eA)
    }
  }
#undef STEP
#undef EPRE

  if (l < 16) {
    if (!tree) {
      sent_vec[b * HH + d] = h;
    } else {
      t_state[b * HH + d] = c;
      t_hidden[b * HH + d] = h;
    }
  }
}

// ---------------------------------------------------------------------------
// Head: tree_out = [t_state | w1*t_hidden + w2*sent_vec]; sigmoid logits ->
// clipped BCE vs one-hot(y); loss = -mean over (B, NC=2) = 128 terms. fp32.
// ---------------------------------------------------------------------------
__global__ __launch_bounds__(128) void final_kernel(
    const int* __restrict__ y, const float* __restrict__ sent_vec,
    const float* __restrict__ t_state, const float* __restrict__ t_hidden,
    const float* __restrict__ Wout, const float* __restrict__ bout,
    const float* __restrict__ w1, const float* __restrict__ w2,
    float* __restrict__ out) {
  int tid = threadIdx.x;  // (b, cls)
  int b = tid >> 1, cls = tid & 1;
  float W1 = w1[0], W2 = w2[0];
  const float* wrow = Wout + cls * 256;
  float acc = bout[cls];
  for (int j = 0; j < HH; j++)
    acc += t_state[b * HH + j] * wrow[j];
  for (int j = 0; j < HH; j++)
    acc += (W1 * t_hidden[b * HH + j] + W2 * sent_vec[b * HH + j]) * wrow[128 + j];
  float p = 1.f / (1.f + __expf(-acc));
  p = fminf(1.f - 1e-7f, fmaxf(1e-7f, p));
  int yy = y[b]; yy = yy < 0 ? 0 : (yy > 1 ? 1 : yy);
  float term = (cls == yy) ? __logf(p) : __logf(1.f - p);
  __shared__ float red[128];
  red[tid] = term;
  __syncthreads();
  for (int s = 64; s > 0; s >>= 1) {
    if (tid < s) red[tid] += red[tid + s];
    __syncthreads();
  }
  if (tid == 0) out[0] = -red[0] / 128.f;
}

// ---------------------------------------------------------------------------
extern "C" void kernel_launch(void* const* d_in, const int* in_sizes, int n_in,
                              void* d_out, int out_size, void* d_ws, size_t ws_size,
                              hipStream_t stream) {
  (void)in_sizes; (void)n_in; (void)out_size; (void)ws_size;
  const int*   x       = (const int*)d_in[0];
  const int*   y       = (const int*)d_in[1];
  // d_in[2] = p (unused by reference)
  const int*   lengths = (const int*)d_in[3];
  // d_in[4], d_in[5] = left/right child: fixed left-deep chain (j-1 / -1)
  const float* embed   = (const float*)d_in[6];
  const float* Wih_f   = (const float*)d_in[7];
  const float* Whh_f   = (const float*)d_in[8];
  const float* b_f     = (const float*)d_in[9];
  // d_in[10..12] = backward-LSTM weights (result unused by reference)
  const float* Wiou    = (const float*)d_in[13];
  const float* Uiou    = (const float*)d_in[14];
  const float* biou    = (const float*)d_in[15];
  const float* Wf      = (const float*)d_in[16];
  const float* Uf      = (const float*)d_in[17];
  const float* bfv     = (const float*)d_in[18];
  const float* Wout    = (const float*)d_in[19];
  const float* bout    = (const float*)d_in[20];
  const float* w1      = (const float*)d_in[21];
  const float* w2      = (const float*)d_in[22];

  // Workspace: 3 fp32 [64][128] vectors = 96 KiB.
  float* sent_vec = (float*)d_ws;
  float* t_state  = sent_vec + BN * HH;
  float* t_hidden = t_state + BN * HH;

  chains_kernel<<<128, 512, 0, stream>>>(x, lengths, embed,
                                         Wih_f, Whh_f, b_f,
                                         Wiou, Uiou, biou, Wf, Uf, bfv,
                                         sent_vec, t_state, t_hidden);
  final_kernel<<<1, 128, 0, stream>>>(y, sent_vec, t_state, t_hidden,
                                      Wout, bout, w1, w2, (float*)d_out);
}